// Round 4
// baseline (780.847 us; speedup 1.0000x reference)
//
#include <hip/hip_runtime.h>
#include <hip/hip_bf16.h>
#include <cstdint>
#include <cstddef>

// Problem constants (NeuTraLAD): B=8192, D=512, H=1024, K=11 views.
#define NB 8192
#define ND 512
#define NH 1024
#define NK 11

typedef __bf16 bf16x8 __attribute__((ext_vector_type(8)));
typedef float f32x4 __attribute__((ext_vector_type(4)));

// ---------------------------------------------------------------------------
// Convert f32 -> bf16, 8 elems/thread (float4 x2 in, one 16 B store out).
// ---------------------------------------------------------------------------
__global__ void cvt_f32_bf16x8(const float* __restrict__ in,
                               __hip_bfloat16* __restrict__ out, int n8) {
  int i = blockIdx.x * blockDim.x + threadIdx.x;
  if (i >= n8) return;
  const float4* p = (const float4*)in + (size_t)i * 2;
  float4 a = p[0], b = p[1];
  union {
    __hip_bfloat16 h[8];
    uint4 u;
  } pk;
  pk.h[0] = __float2bfloat16(a.x);
  pk.h[1] = __float2bfloat16(a.y);
  pk.h[2] = __float2bfloat16(a.z);
  pk.h[3] = __float2bfloat16(a.w);
  pk.h[4] = __float2bfloat16(b.x);
  pk.h[5] = __float2bfloat16(b.y);
  pk.h[6] = __float2bfloat16(b.z);
  pk.h[7] = __float2bfloat16(b.w);
  ((uint4*)out)[i] = pk.u;
}

// ---------------------------------------------------------------------------
// ONE preamble launch: all four weight transposes f32 [R,C] -> bf16 [C,R].
// z 0..10 = Wt1 slices, 11..21 = Wt2 slices, 22 = We1, 23 = We2.
// ---------------------------------------------------------------------------
__global__ void transpose_all(const float* __restrict__ Wt1,
                              const float* __restrict__ Wt2,
                              const float* __restrict__ We1,
                              const float* __restrict__ We2,
                              __hip_bfloat16* __restrict__ Wt1t,
                              __hip_bfloat16* __restrict__ Wt2t,
                              __hip_bfloat16* __restrict__ We1t,
                              __hip_bfloat16* __restrict__ We2t) {
  __shared__ float tile[32][33];
  const int z = blockIdx.z;
  int R, C;
  const float* inb;
  __hip_bfloat16* outb;
  if (z < NK) {
    R = ND; C = NH;
    inb = Wt1 + (size_t)z * ND * NH;
    outb = Wt1t + (size_t)z * ND * NH;
  } else if (z < 2 * NK) {
    R = NH; C = ND;
    inb = Wt2 + (size_t)(z - NK) * NH * ND;
    outb = Wt2t + (size_t)(z - NK) * NH * ND;
  } else if (z == 2 * NK) {
    R = ND; C = NH;
    inb = We1; outb = We1t;
  } else {
    R = NH; C = NH;
    inb = We2; outb = We2t;
  }
  int cx = blockIdx.x * 32 + threadIdx.x;
  int ry = blockIdx.y * 32;
  if (blockIdx.x * 32 >= C || ry >= R) return;  // uniform early-out
  for (int j = threadIdx.y; j < 32; j += 8)
    tile[j][threadIdx.x] = inb[(size_t)(ry + j) * C + cx];
  __syncthreads();
  int ox = ry + threadIdx.x;
  int oy = blockIdx.x * 32;
  for (int j = threadIdx.y; j < 32; j += 8)
    outb[(size_t)(oy + j) * R + ox] = __float2bfloat16(tile[threadIdx.x][j]);
}

__device__ __forceinline__ float fast_tanh(float x) {
  float e = __expf(2.0f * x);
  return 1.0f - 2.0f / (e + 1.0f);
}

// ---------------------------------------------------------------------------
// MFMA GEMM (NT): C[M,N] = act(A[M,Kd] * Bt[N,Kd]^T + bias[N])
// R16 config FROZEN (session best 735.8 us; G4-class = 110.5 us = 932 TF =
// the m97-structure ceiling). All four GEMMs at 256x128, 512 thr, 16x16x32
// MFMA, 48 KiB LDS -> 3 blocks/CU (inter-block overlap IS the latency
// hiding, m114).
// Experiment ledger (do NOT re-attempt without new evidence):
//   R7: direct-B / single-barrier pipelining — regression.
//   R12: all-256x256 (1024 thr + 64 KB LDS) — crash, cause unisolated.
//   R13: G4-only 256x256 legacy — 831 us (1 blk/CU loses 3-blk overlap).
//   R14: 8-phase port (counted vmcnt(6), setprio, 128 KB LDS) — 939 us,
//        MfmaUtil 30. R16 post-analysis: WAR constraints force the stage
//        spread to ~R14's schedule anyway, i.e. the faithful template WAS
//        tried; m201's residual levers (st_16x32 subtile ds-reads, SGPR
//        base hoisting) aren't reconstructible by guessing. LINE CLOSED.
//   R15: MFMA 32x32x16 swap — 876 us, bank conflicts 0 -> 1.26e7 (the
//        lane>>5-keyed b128 pattern conflicts; 16x16 pattern is clean —
//        confirmed by R16's return to 0). Reverted.
// EPI: 1 = tanh->bf16, 2 = relu->bf16, 3 = plain->bf16
// ---------------------------------------------------------------------------
template <int EPI, int BK, int TM, int TN>
__global__ __launch_bounds__((TM / 64) * (TN / 64) * 64) void gemm_bt(
    const __hip_bfloat16* __restrict__ A, long sAz, int lda,
    const __hip_bfloat16* __restrict__ Bt, long sBz, int ldb,
    const float* __restrict__ bias, long sBiasZ,
    __hip_bfloat16* __restrict__ C, long sCz, int ldc, int Kd) {
  __shared__ __align__(16) __hip_bfloat16 As[TM * BK];
  __shared__ __align__(16) __hip_bfloat16 Bs[TN * BK];

  const int z = blockIdx.z;
  const __hip_bfloat16* Ab = A + (size_t)z * sAz;
  const __hip_bfloat16* Bb = Bt + (size_t)z * sBz;
  const float* biasb = bias + (size_t)z * sBiasZ;
  __hip_bfloat16* Cb = C + (size_t)z * sCz;

  const int bm = blockIdx.x, bn = blockIdx.y;  // x = row panel (XCD affinity)
  const int t = threadIdx.x;
  constexpr int NWN = TN / 64;
  constexpr int T = (TM / 64) * NWN * 64;  // threads
  const int lane = t & 63, w = t >> 6;
  const int wm = w / NWN, wn = w % NWN;
  const int r = lane & 15, q = lane >> 4;

  f32x4 acc[4][4] = {};

  // Staging chunk->(row, global-offset) with XOR swizzle (self-inverse).
  auto chunk_row = [&](int c) {
    return (BK == 32) ? (c >> 2) : (c >> 3);
  };
  auto chunk_gofs = [&](int c, int row) {
    return (BK == 32) ? ((((c & 3) ^ ((row >> 1) & 3)) * 8))
                      : ((((c & 7) ^ (row & 7)) * 8));
  };
  constexpr int CPTA = TM * BK / 8 / T;  // A chunks per thread
  constexpr int CPTB = TN * BK / 8 / T;  // B chunks per thread
  const size_t rowA = (size_t)bm * TM, rowB = (size_t)bn * TN;

  for (int k0 = 0; k0 < Kd; k0 += BK) {
#pragma unroll
    for (int m = 0; m < CPTA; ++m) {
      int c = t + m * T;
      int rw = chunk_row(c);
      __builtin_amdgcn_global_load_lds(
          (const __attribute__((address_space(1))) void*)(Ab + (rowA + rw) * lda + k0 + chunk_gofs(c, rw)),
          (__attribute__((address_space(3))) void*)(As + c * 8), 16, 0, 0);
    }
#pragma unroll
    for (int m = 0; m < CPTB; ++m) {
      int c = t + m * T;
      int rw = chunk_row(c);
      __builtin_amdgcn_global_load_lds(
          (const __attribute__((address_space(1))) void*)(Bb + (rowB + rw) * ldb + k0 + chunk_gofs(c, rw)),
          (__attribute__((address_space(3))) void*)(Bs + c * 8), 16, 0, 0);
    }
    __syncthreads();

#pragma unroll
    for (int ks = 0; ks < BK / 32; ++ks) {
      bf16x8 af[4], bfr[4];
#pragma unroll
      for (int mt = 0; mt < 4; ++mt) {
        int tr = wm * 64 + mt * 16 + r;
        int sl;
        if constexpr (BK == 32) sl = q ^ ((tr >> 1) & 3);
        else sl = (ks * 4 + q) ^ (tr & 7);
        af[mt] = *(const bf16x8*)&As[tr * BK + sl * 8];
      }
#pragma unroll
      for (int nt = 0; nt < 4; ++nt) {
        int tr = wn * 64 + nt * 16 + r;
        int sl;
        if constexpr (BK == 32) sl = q ^ ((tr >> 1) & 3);
        else sl = (ks * 4 + q) ^ (tr & 7);
        bfr[nt] = *(const bf16x8*)&Bs[tr * BK + sl * 8];
      }
#pragma unroll
      for (int mt = 0; mt < 4; ++mt)
#pragma unroll
        for (int nt = 0; nt < 4; ++nt)
          acc[mt][nt] = __builtin_amdgcn_mfma_f32_16x16x32_bf16(
              bfr[nt], af[mt], acc[mt][nt], 0, 0, 0);
    }
    __syncthreads();
  }

  // Epilogue (operand-swapped): lane holds M-row = mt*16 + r, N-cols =
  // nt*16 + q*4 + j (consecutive) -> 8 B packed stores.
  const int colg0 = bn * TN + wn * 64;
  const int rowg0 = bm * TM + wm * 64;
#pragma unroll
  for (int mt = 0; mt < 4; ++mt) {
    int row = rowg0 + mt * 16 + r;
#pragma unroll
    for (int nt = 0; nt < 4; ++nt) {
      int col = colg0 + nt * 16 + q * 4;
      const f32x4 bv = *(const f32x4*)&biasb[col];
      union {
        __hip_bfloat16 h[4];
        uint2 u;
      } pk;
#pragma unroll
      for (int j = 0; j < 4; ++j) {
        float v = acc[mt][nt][j] + bv[j];
        if (EPI == 1) v = fast_tanh(v);
        if (EPI == 2) v = fmaxf(v, 0.0f);
        pk.h[j] = __float2bfloat16(v);
      }
      *(uint2*)&Cb[(size_t)row * ldc + col] = pk.u;
    }
  }
}

// ---------------------------------------------------------------------------
// R17 final_gram v2: zc laid [Bc][12][NH]. Block = 512 thr = 2 b's x 4
// waves. Each wave owns NH/4 = 256 cols of its b -> 8 K-steps (was 16 with
// 2 waves), all 8 loads prefetched before the MFMA chain; 4 partial Grams
// reduced in LDS. Theory: final_gram is latency/parallelism-bound (zc is
// L3-resident; BW floor ~16 us/chunk), so 2x waves per b + halved chain +
// batched loads should land near the floor.
// ---------------------------------------------------------------------------
__global__ __launch_bounds__(512) void final_gram(
    const __hip_bfloat16* __restrict__ zc, float* __restrict__ out, int Bc) {
  __shared__ float Gs[2][4][16][16];
  const int t = threadIdx.x;
  const int w = t >> 6, lane = t & 63;
  const int bi = w >> 2;   // b within block (0..1)
  const int hh = w & 3;    // quarter-H slice (0..3)
  const int b = blockIdx.x * 2 + bi;
  const int r = lane & 15;
  const int q = lane >> 4;

  const int rs = r < 12 ? r : 11;  // address clamp only; r>=12 contributes 0
  const __hip_bfloat16* base =
      zc + ((size_t)b * 12 + rs) * NH + hh * (NH / 4) + q * 8;

  // Prefetch all 8 K-step fragments (32 VGPR), then run the MFMA chain.
  bf16x8 a[8];
#pragma unroll
  for (int i = 0; i < 8; ++i) {
    bf16x8 v = {};
    if (r < 12) v = *(const bf16x8*)(base + i * 32);
    a[i] = v;
  }
  f32x4 acc = {};
#pragma unroll
  for (int i = 0; i < 8; ++i)
    acc = __builtin_amdgcn_mfma_f32_16x16x32_bf16(a[i], a[i], acc, 0, 0, 0);

#pragma unroll
  for (int j = 0; j < 4; ++j) Gs[bi][hh][q * 4 + j][r] = acc[j];
  __syncthreads();

  if (hh == 0) {
    float term = 0.0f;
    if (lane >= 1 && lane < 12) {
      const float(*G0)[16] = Gs[bi][0];
      const float(*G1)[16] = Gs[bi][1];
      const float(*G2)[16] = Gs[bi][2];
      const float(*G3)[16] = Gs[bi][3];
      float nrm[12];
#pragma unroll
      for (int i = 0; i < 12; ++i)
        nrm[i] = fmaxf(
            sqrtf(G0[i][i] + G1[i][i] + G2[i][i] + G3[i][i]), 1e-8f);
      const int k = lane;
      float pos = __expf((G0[0][k] + G1[0][k] + G2[0][k] + G3[0][k]) /
                         (nrm[0] * nrm[k]));
      float neg = 0.0f;
#pragma unroll
      for (int l = 1; l < 12; ++l)
        if (l != k)
          neg += __expf((G0[k][l] + G1[k][l] + G2[k][l] + G3[k][l]) /
                        (nrm[k] * nrm[l]));
      term = __logf(pos / (pos + neg));
    }
#pragma unroll
    for (int m = 1; m < 16; m <<= 1) term += __shfl_xor(term, m);
    if (lane == 0) out[b] = -term;
  }
}

// ---------------------------------------------------------------------------
extern "C" void kernel_launch(void* const* d_in, const int* in_sizes, int n_in,
                              void* d_out, int out_size, void* d_ws,
                              size_t ws_size, hipStream_t stream) {
  const float* x = (const float*)d_in[0];    // [B,D]
  const float* Wt1 = (const float*)d_in[1];  // [K,D,H]
  const float* bt1 = (const float*)d_in[2];  // [K,H]
  const float* Wt2 = (const float*)d_in[3];  // [K,H,D]
  const float* bt2 = (const float*)d_in[4];  // [K,D]
  const float* We1 = (const float*)d_in[5];  // [D,H]
  const float* be1 = (const float*)d_in[6];  // [H]
  const float* We2 = (const float*)d_in[7];  // [H,H]
  const float* be2 = (const float*)d_in[8];  // [H]
  float* out = (float*)d_out;                // [B]

  char* ws = (char*)d_ws;
  size_t off = 0;
  auto alloc = [&](size_t bytes) {
    void* p = ws + off;
    off += (bytes + 255) & ~(size_t)255;
    return p;
  };

  // Persistent bf16 weight transposes (~26 MB)
  __hip_bfloat16* Wt1t = (__hip_bfloat16*)alloc((size_t)NK * NH * ND * 2);  // [K,H,D]
  __hip_bfloat16* Wt2t = (__hip_bfloat16*)alloc((size_t)NK * ND * NH * 2);  // [K,D,H]
  __hip_bfloat16* We1t = (__hip_bfloat16*)alloc((size_t)NH * ND * 2);       // [H,D]
  __hip_bfloat16* We2t = (__hip_bfloat16*)alloc((size_t)NH * NH * 2);       // [H,H]
  const size_t wbytes = off;

  // Pick largest batch chunk Bc (ws in [228,253) MB -> Bc=4096).
  // zc ALIASES txc's region (txc dead after G3).
  int Bc = NB;
  while (Bc > 256) {
    size_t need = wbytes + 2 * ((size_t)12 * Bc * NH * 2) + 4096;
    if (need <= ws_size) break;
    Bc >>= 1;
  }
  __hip_bfloat16* region0 = (__hip_bfloat16*)alloc((size_t)12 * Bc * NH * 2);
  __hip_bfloat16* h1 = (__hip_bfloat16*)alloc((size_t)12 * Bc * NH * 2);
  __hip_bfloat16* txc = region0;  // [12, Bc, ND] during G1..G3
  __hip_bfloat16* zc = region0;   // [Bc, 12, NH] during G4..final

  // One-time: all weight transposes in ONE launch
  transpose_all<<<dim3(NH / 32, NH / 32, 2 * NK + 2), dim3(32, 8), 0,
                  stream>>>(Wt1, Wt2, We1, We2, Wt1t, Wt2t, We1t, We2t);

  for (int cs = 0; cs < NB; cs += Bc) {
    // 1) x chunk -> bf16 (slice 0 of txc), 8 elems/thread
    cvt_f32_bf16x8<<<(Bc * ND / 8) / 256, 256, 0, stream>>>(
        x + (size_t)cs * ND, txc, Bc * ND / 8);
    // 2) G1: hx_k = tanh(x @ Wt1[k] + bt1) -> h1 slices 0..10
    gemm_bt<1, 64, 256, 128><<<dim3(Bc / 256, NH / 128, NK), 512, 0,
                               stream>>>(
        txc, 0L, ND, Wt1t, (long)NH * ND, ND, bt1, (long)NH, h1,
        (long)Bc * NH, NH, ND);
    // 3) G2: tx_k = hx_k @ Wt2[k] + bt2 -> txc slices 1..11
    gemm_bt<3, 64, 256, 128><<<dim3(Bc / 256, ND / 128, NK), 512, 0,
                               stream>>>(
        h1, (long)Bc * NH, NH, Wt2t, (long)ND * NH, NH, bt2, (long)ND,
        txc + (size_t)Bc * ND, (long)Bc * ND, ND, NH);
    // 4) G3: e1_s = relu(tx_s @ We1 + be1) -> h1 slices 0..11
    gemm_bt<2, 64, 256, 128><<<dim3(Bc / 256, NH / 128, 12), 512, 0,
                               stream>>>(
        txc, (long)Bc * ND, ND, We1t, 0L, ND, be1, 0L, h1, (long)Bc * NH,
        NH, ND);
    // 5) G4: z_s -> zc [b][s][h] (sCz=NH, ldc=12NH; Kd=1024) — R11 config
    gemm_bt<3, 64, 256, 128><<<dim3(Bc / 256, NH / 128, 12), 512, 0,
                               stream>>>(
        h1, (long)Bc * NH, NH, We2t, 0L, NH, be2, 0L, zc, (long)NH,
        12 * NH, NH);
    // 6) final score — v2: 2 b's x 4 waves, 512 thr
    final_gram<<<Bc / 2, 512, 0, stream>>>(zc, out + cs, Bc);
  }
}

// Round 5
// 733.719 us; speedup vs baseline: 1.0642x; 1.0642x over previous
//
#include <hip/hip_runtime.h>
#include <hip/hip_bf16.h>
#include <cstdint>
#include <cstddef>

// Problem constants (NeuTraLAD): B=8192, D=512, H=1024, K=11 views.
#define NB 8192
#define ND 512
#define NH 1024
#define NK 11

typedef __bf16 bf16x8 __attribute__((ext_vector_type(8)));
typedef float f32x4 __attribute__((ext_vector_type(4)));

// ---------------------------------------------------------------------------
// Convert f32 -> bf16, 8 elems/thread (float4 x2 in, one 16 B store out).
// ---------------------------------------------------------------------------
__global__ void cvt_f32_bf16x8(const float* __restrict__ in,
                               __hip_bfloat16* __restrict__ out, int n8) {
  int i = blockIdx.x * blockDim.x + threadIdx.x;
  if (i >= n8) return;
  const float4* p = (const float4*)in + (size_t)i * 2;
  float4 a = p[0], b = p[1];
  union {
    __hip_bfloat16 h[8];
    uint4 u;
  } pk;
  pk.h[0] = __float2bfloat16(a.x);
  pk.h[1] = __float2bfloat16(a.y);
  pk.h[2] = __float2bfloat16(a.z);
  pk.h[3] = __float2bfloat16(a.w);
  pk.h[4] = __float2bfloat16(b.x);
  pk.h[5] = __float2bfloat16(b.y);
  pk.h[6] = __float2bfloat16(b.z);
  pk.h[7] = __float2bfloat16(b.w);
  ((uint4*)out)[i] = pk.u;
}

// ---------------------------------------------------------------------------
// ONE preamble launch: all four weight transposes f32 [R,C] -> bf16 [C,R].
// z 0..10 = Wt1 slices, 11..21 = Wt2 slices, 22 = We1, 23 = We2.
// ---------------------------------------------------------------------------
__global__ void transpose_all(const float* __restrict__ Wt1,
                              const float* __restrict__ Wt2,
                              const float* __restrict__ We1,
                              const float* __restrict__ We2,
                              __hip_bfloat16* __restrict__ Wt1t,
                              __hip_bfloat16* __restrict__ Wt2t,
                              __hip_bfloat16* __restrict__ We1t,
                              __hip_bfloat16* __restrict__ We2t) {
  __shared__ float tile[32][33];
  const int z = blockIdx.z;
  int R, C;
  const float* inb;
  __hip_bfloat16* outb;
  if (z < NK) {
    R = ND; C = NH;
    inb = Wt1 + (size_t)z * ND * NH;
    outb = Wt1t + (size_t)z * ND * NH;
  } else if (z < 2 * NK) {
    R = NH; C = ND;
    inb = Wt2 + (size_t)(z - NK) * NH * ND;
    outb = Wt2t + (size_t)(z - NK) * NH * ND;
  } else if (z == 2 * NK) {
    R = ND; C = NH;
    inb = We1; outb = We1t;
  } else {
    R = NH; C = NH;
    inb = We2; outb = We2t;
  }
  int cx = blockIdx.x * 32 + threadIdx.x;
  int ry = blockIdx.y * 32;
  if (blockIdx.x * 32 >= C || ry >= R) return;  // uniform early-out
  for (int j = threadIdx.y; j < 32; j += 8)
    tile[j][threadIdx.x] = inb[(size_t)(ry + j) * C + cx];
  __syncthreads();
  int ox = ry + threadIdx.x;
  int oy = blockIdx.x * 32;
  for (int j = threadIdx.y; j < 32; j += 8)
    outb[(size_t)(oy + j) * R + ox] = __float2bfloat16(tile[threadIdx.x][j]);
}

__device__ __forceinline__ float fast_tanh(float x) {
  float e = __expf(2.0f * x);
  return 1.0f - 2.0f / (e + 1.0f);
}

// ---------------------------------------------------------------------------
// MFMA GEMM (NT): C[M,N] = act(A[M,Kd] * Bt[N,Kd]^T + bias[N])
// R18: R16 config RE-LOCKED (session best 735.8 us; G4-class = 932 TF =
// the m97-structure ceiling, MfmaUtil 41, conflicts 0). All four GEMMs at
// 256x128, 512 thr, 16x16x32 MFMA, 48 KiB LDS -> 3 blocks/CU.
// Experiment ledger (do NOT re-attempt without new evidence):
//   R7: direct-B / single-barrier pipelining — regression.
//   R12: all-256x256 (1024 thr + 64 KB LDS) — crash, cause unisolated.
//   R13: G4-only 256x256 legacy — 831 us (1 blk/CU loses 3-blk overlap).
//   R14: 8-phase port (counted vmcnt(6), setprio, 128 KB LDS) — 939 us,
//        MfmaUtil 30; faithful-template WAR analysis says the schedule was
//        essentially correct — m201's residual levers aren't
//        reconstructible by guessing. LINE CLOSED.
//   R15: MFMA 32x32x16 swap — 876 us, bank conflicts 0 -> 1.26e7 (the
//        lane>>5-keyed b128 read pattern conflicts; 16x16 is clean).
//   R17: final_gram v2 (4 waves/b, 512 thr, prefetch-8) — total +45 us
//        with GEMMs unchanged-to-faster; final_gram is TLP-saturated and
//        ~10-20 us, NOT the ~100 us residual (residual = G1-G3 efficiency
//        + launch gaps). Latency-fix-in-TLP-regime null (rule #23).
// EPI: 1 = tanh->bf16, 2 = relu->bf16, 3 = plain->bf16
// ---------------------------------------------------------------------------
template <int EPI, int BK, int TM, int TN>
__global__ __launch_bounds__((TM / 64) * (TN / 64) * 64) void gemm_bt(
    const __hip_bfloat16* __restrict__ A, long sAz, int lda,
    const __hip_bfloat16* __restrict__ Bt, long sBz, int ldb,
    const float* __restrict__ bias, long sBiasZ,
    __hip_bfloat16* __restrict__ C, long sCz, int ldc, int Kd) {
  __shared__ __align__(16) __hip_bfloat16 As[TM * BK];
  __shared__ __align__(16) __hip_bfloat16 Bs[TN * BK];

  const int z = blockIdx.z;
  const __hip_bfloat16* Ab = A + (size_t)z * sAz;
  const __hip_bfloat16* Bb = Bt + (size_t)z * sBz;
  const float* biasb = bias + (size_t)z * sBiasZ;
  __hip_bfloat16* Cb = C + (size_t)z * sCz;

  const int bm = blockIdx.x, bn = blockIdx.y;  // x = row panel (XCD affinity)
  const int t = threadIdx.x;
  constexpr int NWN = TN / 64;
  constexpr int T = (TM / 64) * NWN * 64;  // threads
  const int lane = t & 63, w = t >> 6;
  const int wm = w / NWN, wn = w % NWN;
  const int r = lane & 15, q = lane >> 4;

  f32x4 acc[4][4] = {};

  // Staging chunk->(row, global-offset) with XOR swizzle (self-inverse).
  auto chunk_row = [&](int c) {
    return (BK == 32) ? (c >> 2) : (c >> 3);
  };
  auto chunk_gofs = [&](int c, int row) {
    return (BK == 32) ? ((((c & 3) ^ ((row >> 1) & 3)) * 8))
                      : ((((c & 7) ^ (row & 7)) * 8));
  };
  constexpr int CPTA = TM * BK / 8 / T;  // A chunks per thread
  constexpr int CPTB = TN * BK / 8 / T;  // B chunks per thread
  const size_t rowA = (size_t)bm * TM, rowB = (size_t)bn * TN;

  for (int k0 = 0; k0 < Kd; k0 += BK) {
#pragma unroll
    for (int m = 0; m < CPTA; ++m) {
      int c = t + m * T;
      int rw = chunk_row(c);
      __builtin_amdgcn_global_load_lds(
          (const __attribute__((address_space(1))) void*)(Ab + (rowA + rw) * lda + k0 + chunk_gofs(c, rw)),
          (__attribute__((address_space(3))) void*)(As + c * 8), 16, 0, 0);
    }
#pragma unroll
    for (int m = 0; m < CPTB; ++m) {
      int c = t + m * T;
      int rw = chunk_row(c);
      __builtin_amdgcn_global_load_lds(
          (const __attribute__((address_space(1))) void*)(Bb + (rowB + rw) * ldb + k0 + chunk_gofs(c, rw)),
          (__attribute__((address_space(3))) void*)(Bs + c * 8), 16, 0, 0);
    }
    __syncthreads();

#pragma unroll
    for (int ks = 0; ks < BK / 32; ++ks) {
      bf16x8 af[4], bfr[4];
#pragma unroll
      for (int mt = 0; mt < 4; ++mt) {
        int tr = wm * 64 + mt * 16 + r;
        int sl;
        if constexpr (BK == 32) sl = q ^ ((tr >> 1) & 3);
        else sl = (ks * 4 + q) ^ (tr & 7);
        af[mt] = *(const bf16x8*)&As[tr * BK + sl * 8];
      }
#pragma unroll
      for (int nt = 0; nt < 4; ++nt) {
        int tr = wn * 64 + nt * 16 + r;
        int sl;
        if constexpr (BK == 32) sl = q ^ ((tr >> 1) & 3);
        else sl = (ks * 4 + q) ^ (tr & 7);
        bfr[nt] = *(const bf16x8*)&Bs[tr * BK + sl * 8];
      }
#pragma unroll
      for (int mt = 0; mt < 4; ++mt)
#pragma unroll
        for (int nt = 0; nt < 4; ++nt)
          acc[mt][nt] = __builtin_amdgcn_mfma_f32_16x16x32_bf16(
              bfr[nt], af[mt], acc[mt][nt], 0, 0, 0);
    }
    __syncthreads();
  }

  // Epilogue (operand-swapped): lane holds M-row = mt*16 + r, N-cols =
  // nt*16 + q*4 + j (consecutive) -> 8 B packed stores.
  const int colg0 = bn * TN + wn * 64;
  const int rowg0 = bm * TM + wm * 64;
#pragma unroll
  for (int mt = 0; mt < 4; ++mt) {
    int row = rowg0 + mt * 16 + r;
#pragma unroll
    for (int nt = 0; nt < 4; ++nt) {
      int col = colg0 + nt * 16 + q * 4;
      const f32x4 bv = *(const f32x4*)&biasb[col];
      union {
        __hip_bfloat16 h[4];
        uint2 u;
      } pk;
#pragma unroll
      for (int j = 0; j < 4; ++j) {
        float v = acc[mt][nt][j] + bv[j];
        if (EPI == 1) v = fast_tanh(v);
        if (EPI == 2) v = fmaxf(v, 0.0f);
        pk.h[j] = __float2bfloat16(v);
      }
      *(uint2*)&Cb[(size_t)row * ldc + col] = pk.u;
    }
  }
}

// ---------------------------------------------------------------------------
// Final (v1, proven in the 735.8 run): zc laid [Bc][12][NH]; 2 waves per b
// (half-H each), partial Grams summed in LDS. Block = 256 thr = 2 b's.
// R17's v2 (4 waves/b) regressed ~+35 us/dispatch — do not re-attempt.
// ---------------------------------------------------------------------------
__global__ __launch_bounds__(256) void final_gram(
    const __hip_bfloat16* __restrict__ zc, float* __restrict__ out, int Bc) {
  __shared__ float Gs[2][2][16][16];
  const int t = threadIdx.x;
  const int w = t >> 6, lane = t & 63;
  const int bi = w >> 1;
  const int hh = w & 1;
  const int b = blockIdx.x * 2 + bi;
  const int r = lane & 15;
  const int q = lane >> 4;

  const int rs = r < 12 ? r : 11;
  const __hip_bfloat16* base =
      zc + ((size_t)b * 12 + rs) * NH + hh * (NH / 2) + q * 8;

  f32x4 acc = {};
#pragma unroll
  for (int k0 = 0; k0 < NH / 2; k0 += 32) {
    bf16x8 a = {};
    if (r < 12) a = *(const bf16x8*)(base + k0);
    acc = __builtin_amdgcn_mfma_f32_16x16x32_bf16(a, a, acc, 0, 0, 0);
  }

#pragma unroll
  for (int j = 0; j < 4; ++j) Gs[bi][hh][q * 4 + j][r] = acc[j];
  __syncthreads();

  if (hh == 0) {
    float term = 0.0f;
    if (lane >= 1 && lane < 12) {
      const float(*G0)[16] = Gs[bi][0];
      const float(*G1)[16] = Gs[bi][1];
      float nrm[12];
#pragma unroll
      for (int i = 0; i < 12; ++i)
        nrm[i] = fmaxf(sqrtf(G0[i][i] + G1[i][i]), 1e-8f);
      const int k = lane;
      float pos = __expf((G0[0][k] + G1[0][k]) / (nrm[0] * nrm[k]));
      float neg = 0.0f;
#pragma unroll
      for (int l = 1; l < 12; ++l)
        if (l != k) neg += __expf((G0[k][l] + G1[k][l]) / (nrm[k] * nrm[l]));
      term = __logf(pos / (pos + neg));
    }
#pragma unroll
    for (int m = 1; m < 16; m <<= 1) term += __shfl_xor(term, m);
    if (lane == 0) out[b] = -term;
  }
}

// ---------------------------------------------------------------------------
extern "C" void kernel_launch(void* const* d_in, const int* in_sizes, int n_in,
                              void* d_out, int out_size, void* d_ws,
                              size_t ws_size, hipStream_t stream) {
  const float* x = (const float*)d_in[0];    // [B,D]
  const float* Wt1 = (const float*)d_in[1];  // [K,D,H]
  const float* bt1 = (const float*)d_in[2];  // [K,H]
  const float* Wt2 = (const float*)d_in[3];  // [K,H,D]
  const float* bt2 = (const float*)d_in[4];  // [K,D]
  const float* We1 = (const float*)d_in[5];  // [D,H]
  const float* be1 = (const float*)d_in[6];  // [H]
  const float* We2 = (const float*)d_in[7];  // [H,H]
  const float* be2 = (const float*)d_in[8];  // [H]
  float* out = (float*)d_out;                // [B]

  char* ws = (char*)d_ws;
  size_t off = 0;
  auto alloc = [&](size_t bytes) {
    void* p = ws + off;
    off += (bytes + 255) & ~(size_t)255;
    return p;
  };

  // Persistent bf16 weight transposes (~26 MB)
  __hip_bfloat16* Wt1t = (__hip_bfloat16*)alloc((size_t)NK * NH * ND * 2);  // [K,H,D]
  __hip_bfloat16* Wt2t = (__hip_bfloat16*)alloc((size_t)NK * ND * NH * 2);  // [K,D,H]
  __hip_bfloat16* We1t = (__hip_bfloat16*)alloc((size_t)NH * ND * 2);       // [H,D]
  __hip_bfloat16* We2t = (__hip_bfloat16*)alloc((size_t)NH * NH * 2);       // [H,H]
  const size_t wbytes = off;

  // Pick largest batch chunk Bc (ws in [228,253) MB -> Bc=4096).
  // zc ALIASES txc's region (txc dead after G3).
  int Bc = NB;
  while (Bc > 256) {
    size_t need = wbytes + 2 * ((size_t)12 * Bc * NH * 2) + 4096;
    if (need <= ws_size) break;
    Bc >>= 1;
  }
  __hip_bfloat16* region0 = (__hip_bfloat16*)alloc((size_t)12 * Bc * NH * 2);
  __hip_bfloat16* h1 = (__hip_bfloat16*)alloc((size_t)12 * Bc * NH * 2);
  __hip_bfloat16* txc = region0;  // [12, Bc, ND] during G1..G3
  __hip_bfloat16* zc = region0;   // [Bc, 12, NH] during G4..final

  // One-time: all weight transposes in ONE launch
  transpose_all<<<dim3(NH / 32, NH / 32, 2 * NK + 2), dim3(32, 8), 0,
                  stream>>>(Wt1, Wt2, We1, We2, Wt1t, Wt2t, We1t, We2t);

  for (int cs = 0; cs < NB; cs += Bc) {
    // 1) x chunk -> bf16 (slice 0 of txc), 8 elems/thread
    cvt_f32_bf16x8<<<(Bc * ND / 8) / 256, 256, 0, stream>>>(
        x + (size_t)cs * ND, txc, Bc * ND / 8);
    // 2) G1: hx_k = tanh(x @ Wt1[k] + bt1) -> h1 slices 0..10
    gemm_bt<1, 64, 256, 128><<<dim3(Bc / 256, NH / 128, NK), 512, 0,
                               stream>>>(
        txc, 0L, ND, Wt1t, (long)NH * ND, ND, bt1, (long)NH, h1,
        (long)Bc * NH, NH, ND);
    // 3) G2: tx_k = hx_k @ Wt2[k] + bt2 -> txc slices 1..11
    gemm_bt<3, 64, 256, 128><<<dim3(Bc / 256, ND / 128, NK), 512, 0,
                               stream>>>(
        h1, (long)Bc * NH, NH, Wt2t, (long)ND * NH, NH, bt2, (long)ND,
        txc + (size_t)Bc * ND, (long)Bc * ND, ND, NH);
    // 4) G3: e1_s = relu(tx_s @ We1 + be1) -> h1 slices 0..11
    gemm_bt<2, 64, 256, 128><<<dim3(Bc / 256, NH / 128, 12), 512, 0,
                               stream>>>(
        txc, (long)Bc * ND, ND, We1t, 0L, ND, be1, 0L, h1, (long)Bc * NH,
        NH, ND);
    // 5) G4: z_s -> zc [b][s][h] (sCz=NH, ldc=12NH; Kd=1024) — R11 config
    gemm_bt<3, 64, 256, 128><<<dim3(Bc / 256, NH / 128, 12), 512, 0,
                               stream>>>(
        h1, (long)Bc * NH, NH, We2t, 0L, NH, be2, 0L, zc, (long)NH,
        12 * NH, NH);
    // 6) final score — v1
    final_gram<<<Bc / 2, 256, 0, stream>>>(zc, out + cs, Bc);
  }
}